// Round 4
// baseline (640.583 us; speedup 1.0000x reference)
//
#include <hip/hip_runtime.h>

#define HIDDEN 512
#define PL 16            // P * L = 4 * 4
#define NF4 (HIDDEN / 4) // 128 float4 per row

typedef float f32x4 __attribute__((ext_vector_type(4)));

// One block (128 threads = 2 waves) per batch element b.
// Each thread owns one f32x4 slice of every 512-wide row.
__global__ __launch_bounds__(128) void vtbpr_fused(
    const float* __restrict__ user_gama,
    const float* __restrict__ item_gama,
    const float* __restrict__ user_beta,
    const float* __restrict__ item_beta,
    const float* __restrict__ theta_user_visual,
    const float* __restrict__ theta_user_text,
    const float* __restrict__ visual_features,
    const float* __restrict__ textural_features,
    const int* __restrict__ user_idx,
    const int* __restrict__ item_idx,
    const int* __restrict__ path_type,
    float* __restrict__ score_out,
    float* __restrict__ meta_out)
{
    const int b = blockIdx.x;
    const int tid = threadIdx.x;

    const int u  = user_idx[b];
    const int it = item_idx[b];

    __shared__ int pt[PL];
    __shared__ float red[2];
    if (tid < PL) pt[tid] = path_type[b * PL + tid];

    const f32x4* UG = (const f32x4*)(user_gama          + (size_t)u  * HIDDEN);
    const f32x4* IG = (const f32x4*)(item_gama          + (size_t)it * HIDDEN);
    const f32x4* TV = (const f32x4*)(theta_user_visual  + (size_t)u  * HIDDEN);
    const f32x4* TT = (const f32x4*)(theta_user_text    + (size_t)u  * HIDDEN);
    const f32x4* VF = (const f32x4*)(visual_features    + (size_t)b  * HIDDEN);
    const f32x4* XF = (const f32x4*)(textural_features  + (size_t)b  * HIDDEN);

    const f32x4 ugv = UG[tid];
    const f32x4 igv = IG[tid];
    const f32x4 tvv = TV[tid];
    const f32x4 ttv = TT[tid];
    // Streamed once, never reused by any other block: nontemporal loads.
    const f32x4 vfv = __builtin_nontemporal_load(&VF[tid]);
    const f32x4 xfv = __builtin_nontemporal_load(&XF[tid]);

    float p = ugv.x*igv.x + ugv.y*igv.y + ugv.z*igv.z + ugv.w*igv.w
            + tvv.x*vfv.x + tvv.y*vfv.y + tvv.z*vfv.z + tvv.w*vfv.w
            + ttv.x*xfv.x + ttv.y*xfv.y + ttv.z*xfv.z + ttv.w*xfv.w;

    // 64-lane wave shuffle reduce, then combine the 2 waves via LDS.
    #pragma unroll
    for (int off = 32; off > 0; off >>= 1)
        p += __shfl_down(p, off, 64);
    if ((tid & 63) == 0) red[tid >> 6] = p;
    __syncthreads();

    if (tid == 0) {
        score_out[b] = user_beta[u] + item_beta[it] + red[0] + red[1];
    }

    // Metapath fan-out: 16 slots, each a full 512-f32 row selected from
    // {ug, ig, 0}. Stores are f32x4, consecutive tid -> consecutive addr.
    // Nontemporal: 268 MB write-once stream, keep it out of L2/LLC.
    const f32x4 zero = (f32x4)(0.f);
    f32x4* outb = (f32x4*)(meta_out + (size_t)b * (PL * HIDDEN));
    #pragma unroll
    for (int s = 0; s < PL; ++s) {
        const int t = pt[s];
        const f32x4 v = (t == 0) ? ugv : (t == 1) ? igv : zero;
        __builtin_nontemporal_store(v, &outb[s * NF4 + tid]);
    }
}

extern "C" void kernel_launch(void* const* d_in, const int* in_sizes, int n_in,
                              void* d_out, int out_size, void* d_ws, size_t ws_size,
                              hipStream_t stream) {
    const float* user_gama         = (const float*)d_in[0];
    const float* item_gama         = (const float*)d_in[1];
    const float* user_beta         = (const float*)d_in[2];
    const float* item_beta         = (const float*)d_in[3];
    const float* theta_user_visual = (const float*)d_in[4];
    const float* theta_user_text   = (const float*)d_in[5];
    const float* visual_features   = (const float*)d_in[6];
    const float* textural_features = (const float*)d_in[7];
    const int*   user_idx          = (const int*)d_in[8];
    const int*   item_idx          = (const int*)d_in[9];
    const int*   path_type         = (const int*)d_in[10];

    const int B = in_sizes[8];  // 8192

    float* score_out = (float*)d_out;            // B floats
    float* meta_out  = (float*)d_out + B;        // B * 16 * 512 floats

    vtbpr_fused<<<B, 128, 0, stream>>>(
        user_gama, item_gama, user_beta, item_beta,
        theta_user_visual, theta_user_text,
        visual_features, textural_features,
        user_idx, item_idx, path_type,
        score_out, meta_out);
}